// Round 2
// baseline (205.281 us; speedup 1.0000x reference)
//
#include <hip/hip_runtime.h>

// Problem constants (from reference): B=64, S=8192, C=512
#define NROWS (64 * 8192)
#define C 512
#define WEIGHT 2.0f
#define NBLOCKS 2048
#define BLOCK 256                       // 4 waves per block
#define NWAVES (NBLOCKS * 4)            // 8192 waves
#define ITERS (NROWS / (2 * NWAVES))    // 32 iterations, 2 rows per iter (exact)

// Native vector type so __builtin_nontemporal_load compiles (HIP's float4 is a
// struct, which the builtin rejects; ext_vector_type is accepted).
typedef float v4f __attribute__((ext_vector_type(4)));

// Per-row reduce: lane-local argmax over its 8 cols (strict > in ascending
// column order => first occurrence), 6-step shfl_xor butterfly (tie-break:
// smaller index), then a register-based gather of pre[row][t]: the owning
// lane already holds the value; select via cndmask chain + one __shfl.
// All quantities end up wave-uniform, so every lane accumulates identically.
__device__ __forceinline__ void row_reduce(v4f a, v4f b, int lane, int t, float& acc) {
    int baseA = lane * 4;
    float mval = a.x; int midx = baseA;
    if (a.y > mval) { mval = a.y; midx = baseA + 1; }
    if (a.z > mval) { mval = a.z; midx = baseA + 2; }
    if (a.w > mval) { mval = a.w; midx = baseA + 3; }
    int baseB = 256 + lane * 4;
    if (b.x > mval) { mval = b.x; midx = baseB; }
    if (b.y > mval) { mval = b.y; midx = baseB + 1; }
    if (b.z > mval) { mval = b.z; midx = baseB + 2; }
    if (b.w > mval) { mval = b.w; midx = baseB + 3; }

    #pragma unroll
    for (int off = 1; off < 64; off <<= 1) {
        float oval = __shfl_xor(mval, off);
        int   oidx = __shfl_xor(midx, off);
        if (oval > mval || (oval == mval && oidx < midx)) {
            mval = oval; midx = oidx;
        }
    }

    // Register gather of pre[row][t] (t is wave-uniform):
    // col t lives in lane (t&255)>>2, slot a/b by t>=256, element t&3.
    bool hi = t >= 256;
    int  e = t & 3;
    int  owner = (t & 255) >> 2;
    float cx = hi ? b.x : a.x;
    float cy = hi ? b.y : a.y;
    float cz = hi ? b.z : a.z;
    float cw = hi ? b.w : a.w;
    float d0 = (e & 1) ? cy : cx;
    float d1 = (e & 1) ? cw : cz;
    float cand = (e & 2) ? d1 : d0;
    float g = __shfl(cand, owner);

    int d = midx - t;
    float w = (d == 1 || d == -1) ? WEIGHT : 1.0f;
    acc += w * g;
}

__global__ __launch_bounds__(BLOCK) void nll_rows_kernel(
    const float* __restrict__ pre,
    const int* __restrict__ y_true,
    float* __restrict__ partial) {
    const int lane = threadIdx.x & 63;
    const int wave = threadIdx.x >> 6;        // 0..3
    const int gwave = blockIdx.x * 4 + wave;  // global wave id

    const v4f* p = reinterpret_cast<const v4f*>(pre) + (size_t)gwave * (C / 4);
    const size_t rstride = (size_t)NWAVES * (C / 4);  // v4f elements per row-step

    float acc = 0.0f;
    int row = gwave;
    for (int it = 0; it < ITERS; ++it) {
        const v4f* p0 = p;
        const v4f* p1 = p + rstride;
        // Issue all 4 row loads + both y_true loads before any reduce work:
        // 2 rows of VMEM in flight per wave; data is read exactly once, so
        // nontemporal (no L2 retention) is safe.
        v4f a0 = __builtin_nontemporal_load(p0 + lane);
        v4f b0 = __builtin_nontemporal_load(p0 + 64 + lane);
        v4f a1 = __builtin_nontemporal_load(p1 + lane);
        v4f b1 = __builtin_nontemporal_load(p1 + 64 + lane);
        int t0 = y_true[row];
        int t1 = y_true[row + NWAVES];

        row_reduce(a0, b0, lane, t0, acc);
        row_reduce(a1, b1, lane, t1, acc);

        p += 2 * rstride;
        row += 2 * NWAVES;
    }

    __shared__ float ssum[4];
    if (lane == 0) ssum[wave] = acc;  // acc is wave-uniform; lane 0's copy
    __syncthreads();
    if (threadIdx.x == 0) {
        partial[blockIdx.x] = ssum[0] + ssum[1] + ssum[2] + ssum[3];
    }
}

// Deterministic fixed-order reduction of the block partials.
__global__ __launch_bounds__(256) void nll_reduce_kernel(
    const float* __restrict__ partial, float* __restrict__ out, int n) {
    __shared__ float s[256];
    float acc = 0.0f;
    for (int i = threadIdx.x; i < n; i += 256) acc += partial[i];
    s[threadIdx.x] = acc;
    __syncthreads();
    for (int w = 128; w > 0; w >>= 1) {
        if (threadIdx.x < w) s[threadIdx.x] += s[threadIdx.x + w];
        __syncthreads();
    }
    if (threadIdx.x == 0) out[0] = s[0] * (1.0f / 64.0f);  // divide by B
}

extern "C" void kernel_launch(void* const* d_in, const int* in_sizes, int n_in,
                              void* d_out, int out_size, void* d_ws, size_t ws_size,
                              hipStream_t stream) {
    const float* pre = (const float*)d_in[0];
    const int* y_true = (const int*)d_in[1];
    float* out = (float*)d_out;
    float* partial = (float*)d_ws;  // NBLOCKS floats

    nll_rows_kernel<<<NBLOCKS, BLOCK, 0, stream>>>(pre, y_true, partial);
    nll_reduce_kernel<<<1, 256, 0, stream>>>(partial, out, NBLOCKS);
}